// Round 5
// baseline (5868.074 us; speedup 1.0000x reference)
//
#include <hip/hip_runtime.h>
#include <hip/hip_bf16.h>
#include <hip/hip_fp16.h>

// StepWiseMLPAutoEncoder.
// Encoder is non-recurrent (scan carry = input column) -> big batched MFMA GEMMs.
// Decoder: two INDEPENDENT 16-row chains (batch rows are independent recurrences) on
// disjoint persistent WG sets (34 WGs x 2 chains, 128 threads each). Weights pinned in
// padded LDS; per-wave full-K MFMA (no LDS reduction); proven release/acquire agent-fence
// + per-WG-flag barrier. y = a1 @ W2 deferred to one batched GEMM after the loop.
// All internal math fp16 with fp32 MFMA accumulation (mfma_f32_16x16x32_f16).

typedef _Float16 f16x8 __attribute__((ext_vector_type(8)));
typedef float f32x4 __attribute__((ext_vector_type(4)));
typedef unsigned short u16;
typedef unsigned int u32;

#define MFMA(a, b, c) __builtin_amdgcn_mfma_f32_16x16x32_f16((a), (b), (c), 0, 0, 0)

__device__ __forceinline__ float h2f(u16 u) { __half h; __builtin_memcpy(&h, &u, 2); return __half2float(h); }
__device__ __forceinline__ u16 f2h(float f) { __half h = __float2half(f); u16 u; __builtin_memcpy(&u, &h, 2); return u; }

// ---------------- zero ----------------
__global__ __launch_bounds__(256) void zero_u16_kernel(u16* p, int n) {
  int i = blockIdx.x * 256 + threadIdx.x;
  if (i < n) p[i] = 0;
}
__global__ __launch_bounds__(256) void zero_u32_kernel(int* p, int n) {
  int i = blockIdx.x * 256 + threadIdx.x;
  if (i < n) p[i] = 0;
}

// ---------------- transpose x -> xT ----------------
// x: [32][1024][512] f32 ; xT: [(512+1)*32][1024] f16, xT[(t+1)*32+b][f] = x[b][f][t]
__global__ __launch_bounds__(256) void transpose_kernel(const float* __restrict__ x, u16* __restrict__ xT) {
  __shared__ float tile[64][65];
  int b = blockIdx.z, f0 = blockIdx.x * 64, t0 = blockIdx.y * 64;
  const float* xp = x + (size_t)b * (1024 * 512);
  for (int rep = 0; rep < 16; ++rep) {
    int e = rep * 256 + threadIdx.x;
    int fi = e >> 6, tj = e & 63;
    tile[fi][tj] = xp[(size_t)(f0 + fi) * 512 + t0 + tj];
  }
  __syncthreads();
  for (int rep = 0; rep < 16; ++rep) {
    int e = rep * 256 + threadIdx.x;
    int tj = e >> 6, fi = e & 63;
    xT[(size_t)((t0 + tj + 1) * 32 + b) * 1024 + f0 + fi] = f2h(tile[fi][tj]);
  }
}

// ---------------- weight packing ----------------
// out[(kq*Np + n)*8 + v] = W[row0 + kq*8+v][n] (0 outside real range), fp16
__global__ __launch_bounds__(256) void pack_w_kernel(const float* __restrict__ W, int ldw, int row0,
                                                     int Kr, int Nr, u16* __restrict__ out, int Np, int total) {
  int id = blockIdx.x * 256 + threadIdx.x;
  if (id >= total) return;
  int kq = id / Np, n = id % Np;
  union { u16 v[8]; uint4 q; } un;
#pragma unroll
  for (int j = 0; j < 8; ++j) {
    int k = kq * 8 + j;
    float f = (k < Kr && n < Nr) ? W[(size_t)(row0 + k) * ldw + n] : 0.f;
    un.v[j] = f2h(f);
  }
  *(uint4*)(out + (size_t)id * 8) = un.q;
}

// ---------------- c2x = db2 @ dw0[64:1088,:] ----------------
__global__ __launch_bounds__(256) void c2x_kernel(const float* __restrict__ dw0, const float* __restrict__ db2,
                                                  float* __restrict__ c2x) {
  int n = blockIdx.x * 256 + threadIdx.x;
  if (n >= 1152) return;
  float s = 0.f;
  if (n < 1067) {
    for (int k = 0; k < 1024; ++k) s += db2[k] * dw0[(size_t)(64 + k) * 1067 + n];
  }
  c2x[n] = s;
}

// ---------------- dw2 (f32 [1046][1024]) -> f16 row-major [1152][1024], rows >=1046 zero ----
__global__ __launch_bounds__(256) void cvt_a_kernel(const float* __restrict__ src, u16* __restrict__ dst) {
  int i = blockIdx.x * 256 + threadIdx.x;  // 1152*1024 total
  int r = i >> 10;
  dst[i] = f2h(r < 1046 ? src[i] : 0.f);
}

// ---------------- generic GEMM ----------------
// C[M x Np] = act( A[M x Kp] @ Wpacked + bias + t-terms ), A fp16 row-major, W packed [Kp/8][Np][8]
// TWOSRC: A row r, col k<1024 -> A[r][k]; k>=1024 -> A[r+32][k-1024]  (encoder concat trick)
// T1: += (t/512) * wt1[n]   T2: += (t>0) * wt2[n]   with t = row>>5
// PACKO: output in decoder-packed layout out[((r>>3)*Np + col)*8 + (r&7)]
template <int TWOSRC, int ACT, int T1, int T2, int PACKO>
__global__ __launch_bounds__(256) void gemm_kernel(
    const u16* __restrict__ A, int lda,
    const u16* __restrict__ Wp, int Np,
    const float* __restrict__ bias, int nb,
    const float* __restrict__ wt1, int nw1,
    const float* __restrict__ wt2, int nw2,
    u16* __restrict__ out, int ldo, int Kp) {
  __shared__ u16 As[128][72];
  __shared__ u16 Bs[8 * 64 * 8];
  const int tid = threadIdx.x;
  const int bx = blockIdx.x, by = blockIdx.y;
  const int m0 = by * 128, n0 = bx * 64;
  const int l = tid & 63, wv = tid >> 6, lm = l & 15, lg = l >> 4;
  f32x4 acc[2][4] = {};
  for (int k0 = 0; k0 < Kp; k0 += 64) {
#pragma unroll
    for (int c = 0; c < 4; ++c) {
      int idx = c * 256 + tid;
      int row = idx >> 3, seg = idx & 7;
      int kk = k0 + seg * 8;
      const u16* ap;
      if (TWOSRC) {
        int half = (kk >= 1024) ? 1 : 0;
        ap = A + (size_t)(m0 + row + half * 32) * lda + (kk - half * 1024);
      } else {
        ap = A + (size_t)(m0 + row) * lda + kk;
      }
      *(uint4*)&As[row][seg * 8] = *(const uint4*)ap;
    }
#pragma unroll
    for (int c = 0; c < 2; ++c) {
      int idx = c * 256 + tid;
      int e0 = idx * 8;
      int kq = e0 >> 9, inner = e0 & 511;
      const u16* gp = Wp + (size_t)((k0 >> 3) + kq) * (Np * 8) + n0 * 8 + inner;
      *(uint4*)(Bs + e0) = *(const uint4*)gp;
    }
    __syncthreads();
#pragma unroll
    for (int ks = 0; ks < 2; ++ks) {
      f16x8 af0 = *(const f16x8*)&As[wv * 32 + lm][ks * 32 + lg * 8];
      f16x8 af1 = *(const f16x8*)&As[wv * 32 + 16 + lm][ks * 32 + lg * 8];
#pragma unroll
      for (int nf = 0; nf < 4; ++nf) {
        f16x8 bfr = *(const f16x8*)(Bs + ((ks * 4 + lg) * 64 + nf * 16 + lm) * 8);
        acc[0][nf] = MFMA(af0, bfr, acc[0][nf]);
        acc[1][nf] = MFMA(af1, bfr, acc[1][nf]);
      }
    }
    __syncthreads();
  }
#pragma unroll
  for (int mr = 0; mr < 2; ++mr) {
    int rb = m0 + wv * 32 + mr * 16;
    int tt = rb >> 5;
#pragma unroll
    for (int nf = 0; nf < 4; ++nf) {
      int col = n0 + nf * 16 + lm;
      float bv = (col < nb) ? bias[col] : 0.f;
      if (T1) bv += (float)tt * (1.f / 512.f) * ((col < nw1) ? wt1[col] : 0.f);
      if (T2) bv += ((tt > 0) ? 1.f : 0.f) * ((col < nw2) ? wt2[col] : 0.f);
#pragma unroll
      for (int v = 0; v < 4; ++v) {
        float xv = acc[mr][nf][v] + bv;
        if (ACT == 1) xv = fmaxf(xv, 0.f);
        if (ACT == 2) xv = tanhf(xv);
        if (PACKO) {
          int r = rb + lg * 4 + v;
          out[((size_t)(r >> 3) * Np + col) * 8 + (r & 7)] = f2h(xv);
        } else {
          out[(size_t)(rb + lg * 4 + v) * ldo + col] = f2h(xv);
        }
      }
    }
  }
}

// ---------------- persistent decoder ----------------
// 68 WGs: bid = wgc*2 + chain; chain c handles batch rows c*16..c*16+15, WG cols [wgc*32, wgc*32+32).
#define NWGD 68

// Proven round-3/4 coherence: release(writeback) fence + per-WG flag; poll; acquire(inv) fence.
__device__ __forceinline__ void gbar(int* flags, int bid, int tid, int gen, int chain) {
  __syncthreads();                       // all waves' stores drained (vmcnt 0 at barrier)
  if (tid == 0) {
    __builtin_amdgcn_fence(__ATOMIC_RELEASE, "agent");   // writeback dirty L2 -> LLC
    __hip_atomic_store(flags + bid * 32, gen, __ATOMIC_RELAXED, __HIP_MEMORY_SCOPE_AGENT);
  }
  if (tid < 34) {                        // wave 0 polls this chain's 34 flags
    while (__hip_atomic_load(flags + (tid * 2 + chain) * 32, __ATOMIC_RELAXED, __HIP_MEMORY_SCOPE_AGENT) < gen)
      __builtin_amdgcn_s_sleep(1);
  }
  __syncthreads();
  if (tid == 0) __builtin_amdgcn_fence(__ATOMIC_ACQUIRE, "agent");  // invalidate stale L1/L2
  __syncthreads();
}

__global__ __launch_bounds__(128, 1) void decoder_kernel(
    const u16* __restrict__ W1p, const u16* __restrict__ Mp,
    const u16* __restrict__ hpart, const float* __restrict__ db1,
    u16* actbase, u16* __restrict__ a1buf, int* flags) {
  // padded LDS weight slices: [kq][33 cols][8] (col 32 is pad) -> no 4-way bank alias across lg
  __shared__ __align__(16) u16 w1lds[136 * 33 * 8];   // 71,808 B
  __shared__ __align__(16) u16 mlds[132 * 33 * 8];    // 69,696 B
  const int tid = threadIdx.x, bid = blockIdx.x;
  const int chain = bid & 1, wgc = bid >> 1;
  const int n0 = wgc * 32;
  const int l = tid & 63, wv = tid >> 6, lm = l & 15, lg = l >> 4;
  // stage weight slices (once)
  for (int i = tid; i < 136 * 32; i += 128) {
    int kq = i >> 5, c = i & 31;
    *(uint4*)(w1lds + ((size_t)kq * 33 + c) * 8) = *(const uint4*)(W1p + ((size_t)kq * 1152 + n0 + c) * 8);
  }
  for (int i = tid; i < 132 * 32; i += 128) {
    int kq = i >> 5, c = i & 31;
    *(uint4*)(mlds + ((size_t)kq * 33 + c) * 8) = *(const uint4*)(Mp + ((size_t)kq * 1152 + n0 + c) * 8);
  }
  u16* a0 = actbase + chain * 2 * 17408;   // [136][16][8] packed
  u16* a1 = a0 + 17408;
  const int na = n0 + wv * 16 + lm;        // this lane's output col
  const u16* w1l = w1lds + (size_t)(wv * 16 + lm) * 8;
  const u16* mml = mlds + (size_t)(wv * 16 + lm) * 8;
  int gen = 0;
  // prologue: a0(0) = relu(hpart[0])  (a1(-1)=0 so M-term vanishes); 512 els / 128 thr
#pragma unroll
  for (int j = 0; j < 4; ++j) {
    int e = tid * 4 + j;                   // 0..511 = row*32 + c0
    int row = e >> 5, c0 = e & 31;
    int nc = n0 + c0;
    float v = h2f(hpart[(size_t)(chain * 16 + row) * 1152 + nc]);
    a0[((size_t)(nc >> 3) * 16 + row) * 8 + (nc & 7)] = f2h(fmaxf(v, 0.f));
  }
  gbar(flags, bid, tid, ++gen, chain);
  const float db1v = (na < 1046) ? db1[na] : 0.f;
#pragma unroll 1
  for (int t = 0; t < 512; ++t) {
    // prefetch next hpart slice early (constant data: immune to acquire-inv; hides under MFMA+barrier)
    float hpv[4];
    if (t < 511) {
#pragma unroll
      for (int v = 0; v < 4; ++v)
        hpv[v] = h2f(hpart[(size_t)(t + 1) * 36864 + (size_t)(chain * 16 + lg * 4 + v) * 1152 + na]);
    }
    // ---- phase 1: a1 = relu(a0 @ W1 + db1)  (K=1088, full-K per wave, 2-way acc ILP) ----
    {
      f32x4 accA = {}, accB = {};
#pragma unroll
      for (int i = 0; i < 34; i += 2) {
        int kqa = i * 4 + lg, kqb = (i + 1) * 4 + lg;
        f16x8 afa = *(const f16x8*)(a0 + ((size_t)kqa * 16 + lm) * 8);
        f16x8 bfa = *(const f16x8*)(w1l + (size_t)kqa * 33 * 8);
        accA = MFMA(afa, bfa, accA);
        f16x8 afb = *(const f16x8*)(a0 + ((size_t)kqb * 16 + lm) * 8);
        f16x8 bfb = *(const f16x8*)(w1l + (size_t)kqb * 33 * 8);
        accB = MFMA(afb, bfb, accB);
      }
#pragma unroll
      for (int v = 0; v < 4; ++v) {
        int r = lg * 4 + v;                // D row = (lane>>4)*4 + reg (m89)
        u16 hv = f2h(fmaxf(accA[v] + accB[v] + db1v, 0.f));
        a1[((size_t)(na >> 3) * 16 + r) * 8 + (na & 7)] = hv;
        __builtin_nontemporal_store(hv, a1buf + ((size_t)(t * 32 + chain * 16 + r)) * 1088 + na);
      }
    }
    gbar(flags, bid, tid, ++gen, chain);
    // ---- phase 2: a0' = relu(a1 @ M + hpart[t+1])  (K=1056) ----
    if (t < 511) {
      f32x4 accA = {}, accB = {};
#pragma unroll
      for (int i = 0; i < 32; i += 2) {
        int kqa = i * 4 + lg, kqb = (i + 1) * 4 + lg;
        f16x8 afa = *(const f16x8*)(a1 + ((size_t)kqa * 16 + lm) * 8);
        f16x8 bfa = *(const f16x8*)(mml + (size_t)kqa * 33 * 8);
        accA = MFMA(afa, bfa, accA);
        f16x8 afb = *(const f16x8*)(a1 + ((size_t)kqb * 16 + lm) * 8);
        f16x8 bfb = *(const f16x8*)(mml + (size_t)kqb * 33 * 8);
        accB = MFMA(afb, bfb, accB);
      }
      {  // i = 32 (33rd iter)
        int kq = 32 * 4 + lg;
        f16x8 af = *(const f16x8*)(a1 + ((size_t)kq * 16 + lm) * 8);
        f16x8 bf = *(const f16x8*)(mml + (size_t)kq * 33 * 8);
        accA = MFMA(af, bf, accA);
      }
#pragma unroll
      for (int v = 0; v < 4; ++v) {
        int r = lg * 4 + v;
        a0[((size_t)(na >> 3) * 16 + r) * 8 + (na & 7)] = f2h(fmaxf(accA[v] + accB[v] + hpv[v], 0.f));
      }
      gbar(flags, bid, tid, ++gen, chain);
    }
  }
}

// ---------------- finalize: dout[b][n][t] = ytmp[t*32+b][n]  (db2 folded into y-GEMM bias) ----
__global__ __launch_bounds__(256) void finalize_kernel(const u16* __restrict__ ytmp,
                                                       float* __restrict__ dout) {
  __shared__ float tile[64][65];
  int b = blockIdx.z, n0 = blockIdx.x * 64, t0 = blockIdx.y * 64;
  for (int rep = 0; rep < 16; ++rep) {
    int e = rep * 256 + threadIdx.x;
    int tt = e >> 6, nn = e & 63;
    tile[tt][nn] = h2f(ytmp[(size_t)((t0 + tt) * 32 + b) * 1024 + n0 + nn]);
  }
  __syncthreads();
  for (int rep = 0; rep < 16; ++rep) {
    int e = rep * 256 + threadIdx.x;
    int nn = e >> 6, tt = e & 63;
    dout[((size_t)b * 1024 + n0 + nn) * 512 + t0 + tt] = tile[tt][nn];
  }
}

// ---------------- launch ----------------
extern "C" void kernel_launch(void* const* d_in, const int* in_sizes, int n_in,
                              void* d_out, int out_size, void* d_ws, size_t ws_size,
                              hipStream_t stream) {
  (void)in_sizes; (void)n_in; (void)out_size; (void)ws_size;
  const float* x   = (const float*)d_in[0];
  const float* ew0 = (const float*)d_in[1];
  const float* eb0 = (const float*)d_in[2];
  const float* ew1 = (const float*)d_in[3];
  const float* eb1 = (const float*)d_in[4];
  const float* ew2 = (const float*)d_in[5];
  const float* eb2 = (const float*)d_in[6];
  const float* dw0 = (const float*)d_in[7];
  const float* db0 = (const float*)d_in[8];
  const float* dw1 = (const float*)d_in[9];
  const float* db1 = (const float*)d_in[10];
  const float* dw2 = (const float*)d_in[11];
  const float* db2 = (const float*)d_in[12];

  char* ws = (char*)d_ws;
  u16* xT    = (u16*)(ws + 0);                      // 33.6MB; dead after encoder L0 -> reused as ytmp
  u16* ytmp  = (u16*)(ws + 0);                      // [16384][1024] f16 = 33.5MB
  u16* act2  = (u16*)(ws + 33619968ull);            // 25MB region; sub-allocated after encoder:
  u16* A16   = (u16*)(ws + 33619968ull);            //   dw2 f16 [1152][1024] = 2.36MB
  u16* Mp    = (u16*)(ws + 33619968ull + 2359296ull);   // packed M = 2.65MB
  int* flags = (int*)(ws + 33619968ull + 8388608ull);   // 68*32 ints
  u16* hid   = (u16*)(ws + 58785792ull);            // 16384*64
  u16* hpart = (u16*)(ws + 60882944ull);            // 16384*1152
  u16* We0p  = (u16*)(ws + 98631680ull);
  u16* We1p  = (u16*)(ws + 104398848ull);
  u16* We2p  = (u16*)(ws + 106561536ull);
  u16* Wh0p  = (u16*)(ws + 106659840ull);
  u16* Wd0p  = (u16*)(ws + 106807296ull);
  u16* Wd1p  = (u16*)(ws + 109461504ull);
  u16* Wd2p  = (u16*)(ws + 112115712ull);
  float* c2x = (float*)(ws + 114769920ull);
  u16* actb  = (u16*)(ws + 114774528ull);           // 4 x [136][16][8] f16 = 139,264 B

  u16* act1  = (u16*)d_out;   // [16384][1408] f16 staged in d_out; dead after encoder L1
  u16* a1buf = (u16*)d_out;   // [16384][1088] f16 a1-log, staged in d_out after act1 is dead
  float* dout = (float*)d_out;

  zero_u16_kernel<<<dim3(128), dim3(256), 0, stream>>>(xT, 32 * 1024);  // t=-1 rows of xT

  transpose_kernel<<<dim3(16, 8, 32), dim3(256), 0, stream>>>(x, xT);

  pack_w_kernel<<<dim3(1408), dim3(256), 0, stream>>>(ew0, 1387, 0, 2048, 1387, We0p, 1408, 256 * 1408);
  pack_w_kernel<<<dim3(528),  dim3(256), 0, stream>>>(ew1, 726, 0, 1387, 726, We1p, 768, 176 * 768);
  pack_w_kernel<<<dim3(24),   dim3(256), 0, stream>>>(ew2, 64, 0, 726, 64, We2p, 64, 96 * 64);
  pack_w_kernel<<<dim3(36),   dim3(256), 0, stream>>>(dw0, 1067, 0, 64, 1067, Wh0p, 1152, 8 * 1152);
  pack_w_kernel<<<dim3(648),  dim3(256), 0, stream>>>(dw0, 1067, 64, 1024, 1067, Wd0p, 1152, 144 * 1152);
  pack_w_kernel<<<dim3(648),  dim3(256), 0, stream>>>(dw1, 1046, 0, 1067, 1046, Wd1p, 1152, 144 * 1152);
  pack_w_kernel<<<dim3(648),  dim3(256), 0, stream>>>(dw2, 1024, 0, 1046, 1024, Wd2p, 1152, 144 * 1152);

  c2x_kernel<<<dim3(5), dim3(256), 0, stream>>>(dw0, db2, c2x);

  // encoder
  gemm_kernel<1, 1, 1, 0, 0><<<dim3(22, 128), dim3(256), 0, stream>>>(
      xT, 1024, We0p, 1408, eb0, 1387, ew0 + (size_t)2048 * 1387, 1387, nullptr, 0, act1, 1408, 2048);
  gemm_kernel<0, 1, 0, 0, 0><<<dim3(12, 128), dim3(256), 0, stream>>>(
      act1, 1408, We1p, 768, eb1, 726, nullptr, 0, nullptr, 0, act2, 768, 1408);
  gemm_kernel<0, 2, 0, 0, 0><<<dim3(1, 128), dim3(256), 0, stream>>>(
      act2, 768, We2p, 64, eb2, 64, nullptr, 0, nullptr, 0, hid, 64, 768);
  gemm_kernel<0, 0, 1, 1, 0><<<dim3(18, 128), dim3(256), 0, stream>>>(
      hid, 64, Wh0p, 1152, db0, 1067, dw0 + (size_t)1088 * 1067, 1067, c2x, 1152, hpart, 1152, 64);

  // M = dw2 @ dw0[64:1088]  (act2 region is dead after the hid gemm above)
  cvt_a_kernel<<<dim3(4608), dim3(256), 0, stream>>>(dw2, A16);
  gemm_kernel<0, 0, 0, 0, 1><<<dim3(18, 9), dim3(256), 0, stream>>>(
      A16, 1024, Wd0p, 1152, nullptr, 0, nullptr, 0, nullptr, 0, Mp, 0, 1024);

  zero_u32_kernel<<<dim3(9), dim3(256), 0, stream>>>(flags, NWGD * 32);

  // sequential recurrence: 2 independent 16-row chains (a1-log written to a1buf in d_out)
  decoder_kernel<<<dim3(NWGD), dim3(128), 0, stream>>>(Wd1p, Mp, hpart, db1, actb, a1buf, flags);

  // deferred y = a1 @ W2 + db2  (batched over all t), then transpose into d_out
  gemm_kernel<0, 0, 0, 0, 0><<<dim3(16, 128), dim3(256), 0, stream>>>(
      a1buf, 1088, Wd2p, 1152, db2, 1024, nullptr, 0, nullptr, 0, ytmp, 1024, 1088);
  finalize_kernel<<<dim3(16, 8, 32), dim3(256), 0, stream>>>(ytmp, dout);
}

// Round 7
// 3766.065 us; speedup vs baseline: 1.5581x; 1.5581x over previous
//
#include <hip/hip_runtime.h>
#include <hip/hip_bf16.h>
#include <hip/hip_fp16.h>

// StepWiseMLPAutoEncoder.
// Encoder is non-recurrent (scan carry = input column) -> big batched MFMA GEMMs.
// Decoder recurrence: persistent 67-WG kernel (round-4 structure), weights pinned in LDS.
// Cross-WG activation exchange is FENCE-FREE: all mutable shared data (acts, flags) moves
// through relaxed AGENT-scope atomics, which execute at the LLC (empirically proven by the
// round-4 flag-poll behavior). Ordering: act stores -> vmcnt drain (at __syncthreads) ->
// flag store -> consumer poll -> act loads. No buffer_wbl2 / buffer_inv -> L2 stays warm.
// y = a1 @ W2 deferred to one batched GEMM after the loop.
// All internal math fp16 with fp32 MFMA accumulation (mfma_f32_16x16x32_f16).

typedef _Float16 f16x8 __attribute__((ext_vector_type(8)));
typedef float f32x4 __attribute__((ext_vector_type(4)));
typedef unsigned short u16;
typedef unsigned int u32;
typedef unsigned long long u64;

#define MFMA(a, b, c) __builtin_amdgcn_mfma_f32_16x16x32_f16((a), (b), (c), 0, 0, 0)

__device__ __forceinline__ float h2f(u16 u) { __half h; __builtin_memcpy(&h, &u, 2); return __half2float(h); }
__device__ __forceinline__ u16 f2h(float f) { __half h = __float2half(f); u16 u; __builtin_memcpy(&u, &h, 2); return u; }

// agent-scope (LLC) atomic transport helpers
__device__ __forceinline__ void st_act4(u32* p, u32 v) {
  __hip_atomic_store(p, v, __ATOMIC_RELAXED, __HIP_MEMORY_SCOPE_AGENT);
}
__device__ __forceinline__ f16x8 ld_act16(const u16* p) {
  u64 lo = __hip_atomic_load((const u64*)p, __ATOMIC_RELAXED, __HIP_MEMORY_SCOPE_AGENT);
  u64 hi = __hip_atomic_load((const u64*)(p + 4), __ATOMIC_RELAXED, __HIP_MEMORY_SCOPE_AGENT);
  union { u64 q[2]; f16x8 v; } u;
  u.q[0] = lo; u.q[1] = hi;
  return u.v;
}

// ---------------- zero ----------------
__global__ __launch_bounds__(256) void zero_u16_kernel(u16* p, int n) {
  int i = blockIdx.x * 256 + threadIdx.x;
  if (i < n) p[i] = 0;
}
__global__ __launch_bounds__(256) void zero_u32_kernel(int* p, int n) {
  int i = blockIdx.x * 256 + threadIdx.x;
  if (i < n) p[i] = 0;
}
// zero pad cols 1072..1087 of a1buf [16384][1088]
__global__ __launch_bounds__(256) void zpad_kernel(u16* p) {
  int id = blockIdx.x * 256 + threadIdx.x;  // 16384*16
  int row = id >> 4, col = 1072 + (id & 15);
  p[(size_t)row * 1088 + col] = 0;
}

// ---------------- transpose x -> xT ----------------
// x: [32][1024][512] f32 ; xT: [(512+1)*32][1024] f16, xT[(t+1)*32+b][f] = x[b][f][t]
__global__ __launch_bounds__(256) void transpose_kernel(const float* __restrict__ x, u16* __restrict__ xT) {
  __shared__ float tile[64][65];
  int b = blockIdx.z, f0 = blockIdx.x * 64, t0 = blockIdx.y * 64;
  const float* xp = x + (size_t)b * (1024 * 512);
  for (int rep = 0; rep < 16; ++rep) {
    int e = rep * 256 + threadIdx.x;
    int fi = e >> 6, tj = e & 63;
    tile[fi][tj] = xp[(size_t)(f0 + fi) * 512 + t0 + tj];
  }
  __syncthreads();
  for (int rep = 0; rep < 16; ++rep) {
    int e = rep * 256 + threadIdx.x;
    int tj = e >> 6, fi = e & 63;
    xT[(size_t)((t0 + tj + 1) * 32 + b) * 1024 + f0 + fi] = f2h(tile[fi][tj]);
  }
}

// ---------------- weight packing ----------------
// out[(kq*Np + n)*8 + v] = W[row0 + kq*8+v][n] (0 outside real range), fp16
__global__ __launch_bounds__(256) void pack_w_kernel(const float* __restrict__ W, int ldw, int row0,
                                                     int Kr, int Nr, u16* __restrict__ out, int Np, int total) {
  int id = blockIdx.x * 256 + threadIdx.x;
  if (id >= total) return;
  int kq = id / Np, n = id % Np;
  union { u16 v[8]; uint4 q; } un;
#pragma unroll
  for (int j = 0; j < 8; ++j) {
    int k = kq * 8 + j;
    float f = (k < Kr && n < Nr) ? W[(size_t)(row0 + k) * ldw + n] : 0.f;
    un.v[j] = f2h(f);
  }
  *(uint4*)(out + (size_t)id * 8) = un.q;
}

// ---------------- c2x = db2 @ dw0[64:1088,:] ----------------
__global__ __launch_bounds__(256) void c2x_kernel(const float* __restrict__ dw0, const float* __restrict__ db2,
                                                  float* __restrict__ c2x) {
  int n = blockIdx.x * 256 + threadIdx.x;
  if (n >= 1152) return;
  float s = 0.f;
  if (n < 1067) {
    for (int k = 0; k < 1024; ++k) s += db2[k] * dw0[(size_t)(64 + k) * 1067 + n];
  }
  c2x[n] = s;
}

// ---------------- dw2 (f32 [1046][1024]) -> f16 row-major [1152][1024], rows >=1046 zero ----
__global__ __launch_bounds__(256) void cvt_a_kernel(const float* __restrict__ src, u16* __restrict__ dst) {
  int i = blockIdx.x * 256 + threadIdx.x;  // 1152*1024 total
  int r = i >> 10;
  dst[i] = f2h(r < 1046 ? src[i] : 0.f);
}

// ---------------- generic GEMM ----------------
// C[M x Np] = act( A[M x Kp] @ Wpacked + bias + t-terms ), A fp16 row-major, W packed [Kp/8][Np][8]
// TWOSRC: A row r, col k<1024 -> A[r][k]; k>=1024 -> A[r+32][k-1024]  (encoder concat trick)
// T1: += (t/512) * wt1[n]   T2: += (t>0) * wt2[n]   with t = row>>5
// PACKO: output in decoder-packed layout out[((r>>3)*Np + col)*8 + (r&7)]
template <int TWOSRC, int ACT, int T1, int T2, int PACKO>
__global__ __launch_bounds__(256) void gemm_kernel(
    const u16* __restrict__ A, int lda,
    const u16* __restrict__ Wp, int Np,
    const float* __restrict__ bias, int nb,
    const float* __restrict__ wt1, int nw1,
    const float* __restrict__ wt2, int nw2,
    u16* __restrict__ out, int ldo, int Kp) {
  __shared__ u16 As[128][72];
  __shared__ u16 Bs[8 * 64 * 8];
  const int tid = threadIdx.x;
  const int bx = blockIdx.x, by = blockIdx.y;
  const int m0 = by * 128, n0 = bx * 64;
  const int l = tid & 63, wv = tid >> 6, lm = l & 15, lg = l >> 4;
  f32x4 acc[2][4] = {};
  for (int k0 = 0; k0 < Kp; k0 += 64) {
#pragma unroll
    for (int c = 0; c < 4; ++c) {
      int idx = c * 256 + tid;
      int row = idx >> 3, seg = idx & 7;
      int kk = k0 + seg * 8;
      const u16* ap;
      if (TWOSRC) {
        int half = (kk >= 1024) ? 1 : 0;
        ap = A + (size_t)(m0 + row + half * 32) * lda + (kk - half * 1024);
      } else {
        ap = A + (size_t)(m0 + row) * lda + kk;
      }
      *(uint4*)&As[row][seg * 8] = *(const uint4*)ap;
    }
#pragma unroll
    for (int c = 0; c < 2; ++c) {
      int idx = c * 256 + tid;
      int e0 = idx * 8;
      int kq = e0 >> 9, inner = e0 & 511;
      const u16* gp = Wp + (size_t)((k0 >> 3) + kq) * (Np * 8) + n0 * 8 + inner;
      *(uint4*)(Bs + e0) = *(const uint4*)gp;
    }
    __syncthreads();
#pragma unroll
    for (int ks = 0; ks < 2; ++ks) {
      f16x8 af0 = *(const f16x8*)&As[wv * 32 + lm][ks * 32 + lg * 8];
      f16x8 af1 = *(const f16x8*)&As[wv * 32 + 16 + lm][ks * 32 + lg * 8];
#pragma unroll
      for (int nf = 0; nf < 4; ++nf) {
        f16x8 bfr = *(const f16x8*)(Bs + ((ks * 4 + lg) * 64 + nf * 16 + lm) * 8);
        acc[0][nf] = MFMA(af0, bfr, acc[0][nf]);
        acc[1][nf] = MFMA(af1, bfr, acc[1][nf]);
      }
    }
    __syncthreads();
  }
#pragma unroll
  for (int mr = 0; mr < 2; ++mr) {
    int rb = m0 + wv * 32 + mr * 16;
    int tt = rb >> 5;
#pragma unroll
    for (int nf = 0; nf < 4; ++nf) {
      int col = n0 + nf * 16 + lm;
      float bv = (col < nb) ? bias[col] : 0.f;
      if (T1) bv += (float)tt * (1.f / 512.f) * ((col < nw1) ? wt1[col] : 0.f);
      if (T2) bv += ((tt > 0) ? 1.f : 0.f) * ((col < nw2) ? wt2[col] : 0.f);
#pragma unroll
      for (int v = 0; v < 4; ++v) {
        float xv = acc[mr][nf][v] + bv;
        if (ACT == 1) xv = fmaxf(xv, 0.f);
        if (ACT == 2) xv = tanhf(xv);
        if (PACKO) {
          int r = rb + lg * 4 + v;
          out[((size_t)(r >> 3) * Np + col) * 8 + (r & 7)] = f2h(xv);
        } else {
          out[(size_t)(rb + lg * 4 + v) * ldo + col] = f2h(xv);
        }
      }
    }
  }
}

// ---------------- persistent decoder ----------------
#define NWG 67

// Fence-free barrier: act stores are agent-scope atomics (performed at LLC); the vmcnt
// drain at __syncthreads orders them before the flag store (also agent/LLC). Consumers
// poll the flags at LLC, then read acts at LLC. No cache fences anywhere.
__device__ __forceinline__ void gbar(int* flags, int bid, int tid, int gen) {
  asm volatile("s_waitcnt vmcnt(0)" ::: "memory");   // act stores acked at LLC
  __syncthreads();
  if (tid == 0)
    __hip_atomic_store(flags + bid * 32, gen, __ATOMIC_RELAXED, __HIP_MEMORY_SCOPE_AGENT);
  if (tid < NWG) {
    while (__hip_atomic_load(flags + tid * 32, __ATOMIC_RELAXED, __HIP_MEMORY_SCOPE_AGENT) < gen)
      __builtin_amdgcn_s_sleep(1);
  }
  __syncthreads();
}

// s = (in[32][K-packed] @ Wlds)[thread's 2 cols]; acts packed [kq][32][8]; 4-wave K-split.
__device__ __forceinline__ void dec_mm(const u16* __restrict__ in, const u16* wl,
                                       float (*red)[512], int tid, int lm, int lg, int wv,
                                       int e0, float& s0, float& s1) {
  const int kq0 = wv * 36;
  f32x4 acc0 = {}, acc1 = {};
#pragma unroll
  for (int ks = 0; ks < 9; ++ks) {
    int kq = kq0 + ks * 4 + lg;
    const u16* pa = in + kq * 256 + lm * 8;
    f16x8 a0f = ld_act16(pa);
    f16x8 a1f = ld_act16(pa + 128);
    f16x8 bf = *(const f16x8*)(wl + ((size_t)kq * 16 + lm) * 8);
    acc0 = MFMA(a0f, bf, acc0);
    acc1 = MFMA(a1f, bf, acc1);
  }
  __syncthreads();  // previous red[] readers done
#pragma unroll
  for (int v = 0; v < 4; ++v) {
    red[wv][(lg * 4 + v) * 16 + lm] = acc0[v];
    red[wv][(16 + lg * 4 + v) * 16 + lm] = acc1[v];
  }
  __syncthreads();
  s0 = red[0][e0] + red[1][e0] + red[2][e0] + red[3][e0];
  s1 = red[0][e0 + 1] + red[1][e0 + 1] + red[2][e0 + 1] + red[3][e0 + 1];
}

__global__ __launch_bounds__(256, 1) void decoder_kernel(
    const u16* __restrict__ W1p, const u16* __restrict__ Mp,
    const u16* __restrict__ hpart, const float* __restrict__ db1,
    u16* a0, u16* a1, u16* __restrict__ a1buf, int* flags) {
  __shared__ __align__(16) u16 wlds[2 * 2304 * 8];  // 73,728 B: [W1|M] slices
  __shared__ float red[4][512];                      // 8,192 B
  const int tid = threadIdx.x, bid = blockIdx.x;
  const int l = tid & 63, wv = tid >> 6, lm = l & 15, lg = l >> 4;
  const int n0 = bid * 16;
  // pin weight slices in LDS (once)
  for (int i = tid; i < 2 * 2304; i += 256) {
    int layer = i / 2304, rem = i % 2304, kq = rem >> 4, c = rem & 15;
    const u16* base = (layer == 0) ? W1p : Mp;
    *(uint4*)(wlds + (size_t)i * 8) = *(const uint4*)(base + ((size_t)kq * 1152 + n0 + c) * 8);
  }
  const int e0 = tid * 2, row = e0 >> 4, c0 = e0 & 15, na = n0 + c0;
  u32* a0slot = (u32*)(a0 + (((size_t)(na >> 3) * 32 + row) * 8 + (na & 7)));
  u32* a1slot = (u32*)(a1 + (((size_t)(na >> 3) * 32 + row) * 8 + (na & 7)));
  int gen = 0;
  // prologue: a0(0) = relu(hpart[0])   (a1(-1)=0 so M-term vanishes)
  {
    u32 pk = *(const u32*)(hpart + row * 1152 + na);
    float s0 = fmaxf(h2f((u16)(pk & 0xffff)), 0.f);
    float s1 = fmaxf(h2f((u16)(pk >> 16)), 0.f);
    st_act4(a0slot, (u32)f2h(s0) | ((u32)f2h(s1) << 16));
  }
  gbar(flags, bid, tid, ++gen);
#pragma unroll 1
  for (int t = 0; t < 512; ++t) {
    // ---- phase 1: a1 = relu(a0 @ W1 + db1); log a1 row-major for deferred y-GEMM ----
    float bv0 = (na < 1046) ? db1[na] : 0.f;       // prefetch before MFMA
    float bv1 = (na + 1 < 1046) ? db1[na + 1] : 0.f;
    float s0, s1;
    dec_mm(a0, wlds, red, tid, lm, lg, wv, e0, s0, s1);
    s0 = fmaxf(s0 + bv0, 0.f);
    s1 = fmaxf(s1 + bv1, 0.f);
    u32 opk = (u32)f2h(s0) | ((u32)f2h(s1) << 16);
    st_act4(a1slot, opk);
    __builtin_nontemporal_store(opk, (u32*)(a1buf + ((size_t)(t * 32 + row) * 1088 + na)));
    gbar(flags, bid, tid, ++gen);
    // ---- phase 2: a0' = relu(a1 @ M + hpart[t+1]) ----
    if (t < 511) {
      u32 pk = *(const u32*)(hpart + (size_t)(t + 1) * 36864 + row * 1152 + na);  // prefetch
      dec_mm(a1, wlds + 2304 * 8, red, tid, lm, lg, wv, e0, s0, s1);
      s0 = fmaxf(s0 + h2f((u16)(pk & 0xffff)), 0.f);
      s1 = fmaxf(s1 + h2f((u16)(pk >> 16)), 0.f);
      st_act4(a0slot, (u32)f2h(s0) | ((u32)f2h(s1) << 16));
      gbar(flags, bid, tid, ++gen);
    }
  }
}

// ---------------- finalize: dout[b][n][t] = ytmp[t*32+b][n]  (db2 folded into y-GEMM bias) ----
__global__ __launch_bounds__(256) void finalize_kernel(const u16* __restrict__ ytmp,
                                                       float* __restrict__ dout) {
  __shared__ float tile[64][65];
  int b = blockIdx.z, n0 = blockIdx.x * 64, t0 = blockIdx.y * 64;
  for (int rep = 0; rep < 16; ++rep) {
    int e = rep * 256 + threadIdx.x;
    int tt = e >> 6, nn = e & 63;
    tile[tt][nn] = h2f(ytmp[(size_t)((t0 + tt) * 32 + b) * 1024 + n0 + nn]);
  }
  __syncthreads();
  for (int rep = 0; rep < 16; ++rep) {
    int e = rep * 256 + threadIdx.x;
    int nn = e >> 6, tt = e & 63;
    dout[((size_t)b * 1024 + n0 + nn) * 512 + t0 + tt] = tile[tt][nn];
  }
}

// ---------------- launch ----------------
extern "C" void kernel_launch(void* const* d_in, const int* in_sizes, int n_in,
                              void* d_out, int out_size, void* d_ws, size_t ws_size,
                              hipStream_t stream) {
  (void)in_sizes; (void)n_in; (void)out_size; (void)ws_size;
  const float* x   = (const float*)d_in[0];
  const float* ew0 = (const float*)d_in[1];
  const float* eb0 = (const float*)d_in[2];
  const float* ew1 = (const float*)d_in[3];
  const float* eb1 = (const float*)d_in[4];
  const float* ew2 = (const float*)d_in[5];
  const float* eb2 = (const float*)d_in[6];
  const float* dw0 = (const float*)d_in[7];
  const float* db0 = (const float*)d_in[8];
  const float* dw1 = (const float*)d_in[9];
  const float* db1 = (const float*)d_in[10];
  const float* dw2 = (const float*)d_in[11];
  const float* db2 = (const float*)d_in[12];

  char* ws = (char*)d_ws;
  u16* xT    = (u16*)(ws + 0);                      // 33.6MB; dead after encoder L0 -> reused as ytmp
  u16* ytmp  = (u16*)(ws + 0);                      // [16384][1024] f16 = 33.5MB
  u16* act2  = (u16*)(ws + 33619968ull);            // 25MB region; sub-allocated after encoder:
  u16* A16   = (u16*)(ws + 33619968ull);            //   dw2 f16 [1152][1024] = 2.36MB
  u16* Mp    = (u16*)(ws + 33619968ull + 2359296ull);   // packed M = 2.65MB
  int* flags = (int*)(ws + 33619968ull + 8388608ull);   // 67*32 ints
  u16* hid   = (u16*)(ws + 58785792ull);            // 16384*64
  u16* hpart = (u16*)(ws + 60882944ull);            // 16384*1152
  u16* We0p  = (u16*)(ws + 98631680ull);
  u16* We1p  = (u16*)(ws + 104398848ull);
  u16* We2p  = (u16*)(ws + 106561536ull);
  u16* Wh0p  = (u16*)(ws + 106659840ull);
  u16* Wd0p  = (u16*)(ws + 106807296ull);
  u16* Wd1p  = (u16*)(ws + 109461504ull);
  u16* Wd2p  = (u16*)(ws + 112115712ull);
  float* c2x = (float*)(ws + 114769920ull);
  u16* a0    = (u16*)(ws + 114774528ull);           // 144*32*8 f16, packed
  u16* a1    = (u16*)(ws + 114848256ull);

  u16* act1  = (u16*)d_out;   // [16384][1408] f16 staged in d_out; dead after encoder L1
  u16* a1buf = (u16*)d_out;   // [16384][1088] f16 a1-log, staged in d_out after act1 is dead
  float* dout = (float*)d_out;

  zero_u16_kernel<<<dim3(128), dim3(256), 0, stream>>>(xT, 32 * 1024);  // t=-1 rows of xT
  zero_u16_kernel<<<dim3(288), dim3(256), 0, stream>>>(a0, 2 * 36864);  // a0,a1 contiguous

  transpose_kernel<<<dim3(16, 8, 32), dim3(256), 0, stream>>>(x, xT);

  pack_w_kernel<<<dim3(1408), dim3(256), 0, stream>>>(ew0, 1387, 0, 2048, 1387, We0p, 1408, 256 * 1408);
  pack_w_kernel<<<dim3(528),  dim3(256), 0, stream>>>(ew1, 726, 0, 1387, 726, We1p, 768, 176 * 768);
  pack_w_kernel<<<dim3(24),   dim3(256), 0, stream>>>(ew2, 64, 0, 726, 64, We2p, 64, 96 * 64);
  pack_w_kernel<<<dim3(36),   dim3(256), 0, stream>>>(dw0, 1067, 0, 64, 1067, Wh0p, 1152, 8 * 1152);
  pack_w_kernel<<<dim3(648),  dim3(256), 0, stream>>>(dw0, 1067, 64, 1024, 1067, Wd0p, 1152, 144 * 1152);
  pack_w_kernel<<<dim3(648),  dim3(256), 0, stream>>>(dw1, 1046, 0, 1067, 1046, Wd1p, 1152, 144 * 1152);
  pack_w_kernel<<<dim3(648),  dim3(256), 0, stream>>>(dw2, 1024, 0, 1046, 1024, Wd2p, 1152, 144 * 1152);

  c2x_kernel<<<dim3(5), dim3(256), 0, stream>>>(dw0, db2, c2x);

  // encoder
  gemm_kernel<1, 1, 1, 0, 0><<<dim3(22, 128), dim3(256), 0, stream>>>(
      xT, 1024, We0p, 1408, eb0, 1387, ew0 + (size_t)2048 * 1387, 1387, nullptr, 0, act1, 1408, 2048);
  gemm_kernel<0, 1, 0, 0, 0><<<dim3(12, 128), dim3(256), 0, stream>>>(
      act1, 1408, We1p, 768, eb1, 726, nullptr, 0, nullptr, 0, act2, 768, 1408);
  gemm_kernel<0, 2, 0, 0, 0><<<dim3(1, 128), dim3(256), 0, stream>>>(
      act2, 768, We2p, 64, eb2, 64, nullptr, 0, nullptr, 0, hid, 64, 768);
  gemm_kernel<0, 0, 1, 1, 0><<<dim3(18, 128), dim3(256), 0, stream>>>(
      hid, 64, Wh0p, 1152, db0, 1067, dw0 + (size_t)1088 * 1067, 1067, c2x, 1152, hpart, 1152, 64);

  // M = dw2 @ dw0[64:1088]  (act2 region is dead after the hid gemm above)
  cvt_a_kernel<<<dim3(4608), dim3(256), 0, stream>>>(dw2, A16);
  gemm_kernel<0, 0, 0, 0, 1><<<dim3(18, 9), dim3(256), 0, stream>>>(
      A16, 1024, Wd0p, 1152, nullptr, 0, nullptr, 0, nullptr, 0, Mp, 0, 1024);

  zero_u32_kernel<<<dim3(9), dim3(256), 0, stream>>>(flags, NWG * 32);
  zpad_kernel<<<dim3(1024), dim3(256), 0, stream>>>(a1buf);   // a1buf pad cols (act1 dead now)

  // sequential recurrence (a1-log written to a1buf in d_out)
  decoder_kernel<<<dim3(NWG), dim3(256), 0, stream>>>(Wd1p, Mp, hpart, db1, a0, a1, a1buf, flags);

  // deferred y = a1 @ W2 + db2  (batched over all t), then transpose into d_out
  gemm_kernel<0, 0, 0, 0, 0><<<dim3(16, 128), dim3(256), 0, stream>>>(
      a1buf, 1088, Wd2p, 1152, db2, 1024, nullptr, 0, nullptr, 0, ytmp, 1024, 1088);
  finalize_kernel<<<dim3(16, 8, 32), dim3(256), 0, stream>>>(ytmp, dout);
}